// Round 2
// baseline (422.384 us; speedup 1.0000x reference)
//
#include <hip/hip_runtime.h>
#include <math.h>

#define B_ 4
#define T_ 336
#define N_ 862
#define D_ 64
#define R_ 8
#define K_ 6
#define P_ 96
#define NR 896   // padded n-stride
#define CAP 32   // CSR cap per row
#define NB 864   // padded 862

// workspace float offsets (unchanged layout)
#define OFF_PCQ  0        // 4*192 partial PC/PA
#define OFF_XBP  768      // 4*6*864 xbar t-partials
#define OFF_DINV 21504    // 864
#define OFF_WGT  22368    // 6*3456 (j-major: j*3456 + b*864 + n)
#define OFF_IDX  43104    // 6*3456 int
#define OFF_CNT  63840    // 864 int
#define OFF_CSRV 64704    // 32*864 (j-major)
#define OFF_CSRI 92352    // 32*864 int
#define OFF_P12  120000   // 336*192
#define OFF_PCP  184512   // 336*192 per-t partials of PC/PA
#define OFF_XPT  249024   // 4*192*896 = 688128 (end 937152)
#define OFF_BAR  937216   // 2 int barrier counters (memset to 0 pre-launch)

#define GRID_ 512  // 2 blocks/CU * 256 CUs: co-resident by construction.
                   // launch_bounds(256,2) -> VGPR<=256; LDS 21.5KB*2=43KB<64KB.

// Hand-rolled grid barrier (normal launch; all GRID_ blocks co-resident).
// Release fence (wbl2) before arrival; acquire fence (buffer_inv) after —
// required because per-XCD L2s are not cross-coherent on gfx950.
__device__ __forceinline__ void grid_barrier(int* ctr) {
  __threadfence();          // agent-scope release: flush this block's writes
  __syncthreads();
  if (threadIdx.x == 0) {
    __hip_atomic_fetch_add(ctr, 1, __ATOMIC_ACQ_REL, __HIP_MEMORY_SCOPE_AGENT);
    while (__hip_atomic_load(ctr, __ATOMIC_ACQUIRE, __HIP_MEMORY_SCOPE_AGENT) < GRID_) {
      __builtin_amdgcn_s_sleep(2);
    }
  }
  __syncthreads();
  __threadfence();          // agent-scope acquire: invalidate stale L1/L2 lines
}

__global__ __launch_bounds__(256, 2) void kFused(
    const float* __restrict__ x,    const float* __restrict__ We,
    const float* __restrict__ be,   const float* __restrict__ W1,
    const float* __restrict__ W2,   const float* __restrict__ gate,
    const float* __restrict__ A,    const float* __restrict__ Wgcn,
    const float* __restrict__ ggcn, const float* __restrict__ Whead,
    const float* __restrict__ bhead, float* __restrict__ ws,
    float* __restrict__ out) {
  __shared__ float smem[5376];   // max of: GEMM 768+4608 | topk 2653 | proj 256
  int tid = threadIdx.x;

  // =============== Phase A: proj(336) + xbar partials(336) + CSR/dinv(216) ===
  for (int vb = blockIdx.x; vb < 888; vb += GRID_) {
    __syncthreads();   // protect smem reuse across virtual blocks
    if (vb < 336) {
      // ---- projection for t = vb: P12[t][c], PCP[t][c] (tid<192 active)
      float* sW1 = smem;        // 64
      float* sW2 = smem + 64;   // 64
      float* sCB = smem + 128;  // 64
      float* sWe = smem + 192;  // 64
      int t = vb;
      float g = 1.f / (1.f + expf(-gate[0]));
      if (tid < 64) {
        float a = 0.f;
#pragma unroll
        for (int dd = 0; dd < D_; ++dd) a += We[dd] * Wgcn[dd * D_ + tid];
        sW1[tid] = a;
      } else if (tid < 128) {
        int e = tid - 64;
        float a = 0.f;
#pragma unroll
        for (int dd = 0; dd < D_; ++dd) a += be[dd] * Wgcn[dd * D_ + e];
        sW2[e] = (1.f + g) * a;
      } else if (tid < 192) {
        int e = tid - 128;
        sCB[e] = (1.f + g) * be[e];
        sWe[e] = We[e];
      }
      __syncthreads();
      if (tid < 192) {
        int c = tid, p = c % P_, sel = c / P_;
        const float* cA = sel ? sW1 : sWe;
        const float* cB = sel ? sW2 : sCB;
        const float* wrow = Whead + (size_t)t * D_ * P_ + p;
        float a = 0.f, bacc = 0.f;
#pragma unroll
        for (int e = 0; e < D_; ++e) {
          float w = wrow[(size_t)e * P_];
          a = fmaf(cA[e], w, a);
          bacc = fmaf(cB[e], w, bacc);
        }
        ws[OFF_P12 + t * 192 + c] = a;
        ws[OFF_PCP + t * 192 + c] = bacc;
      }
    } else if (vb < 672) {
      // ---- xbar t-partials: (b, 64-n chunk, t-group of 56), 4 t-subs
      float* part = smem;   // 256
      int iq = vb - 336;
      int b = iq / 84, rem = iq % 84;
      int ch = rem / 6, tg = rem % 6;
      int lane = tid & 63, tsub = tid >> 6;
      int n = ch * 64 + lane;
      float s = 0.f;
      if (n < N_) {
        const float* xp = x + (size_t)(b * T_) * N_ + n;
        int tend = tg * 56 + 56;
#pragma unroll 4
        for (int t = tg * 56 + tsub; t < tend; t += 4) s += xp[(size_t)t * N_];
      }
      part[tid] = s;
      __syncthreads();
      if (tsub == 0 && n < N_)
        ws[OFF_XBP + (size_t)(b * 6 + tg) * NB + n] =
            part[lane] + part[64 + lane] + part[128 + lane] + part[192 + lane];
    } else {
      // ---- CSR + dinv: 4 rows per block, one per wave
      int lane = tid & 63, wv = tid >> 6;
      int n = (vb - 672) * 4 + wv;
      if (n < N_) {
        const float* ap = A + (size_t)n * N_;
        float* vout = ws + OFF_CSRV;
        int* iout = (int*)(ws + OFF_CSRI);
        float s = 0.f;
        int total = 0;
        for (int base = 0; base < N_; base += 64) {
          int m = base + lane;
          float a = (m < N_) ? ap[m] : 0.f;
          s += a;
          bool nz = (a != 0.f);
          unsigned long long mask = __ballot(nz);
          int pos = __popcll(mask & ((1ull << lane) - 1ull));
          if (nz) {
            int slot = total + pos;
            if (slot < CAP) { vout[slot * NB + n] = a; iout[slot * NB + n] = m; }
          }
          total += __popcll(mask);
        }
        for (int off = 32; off; off >>= 1) s += __shfl_down(s, off);
        if (lane == 0) {
          ws[OFF_DINV + n] = (s > 0.f) ? (1.f / sqrtf(s)) : 0.f;
          ((int*)(ws + OFF_CNT))[n] = (total <= CAP) ? total : -1;
        }
      }
    }
  }

  grid_barrier((int*)(ws + OFF_BAR));

  // =============== Phase B: GEMM(432) + topk(4) + PC/PA partials(4) ==========
  for (int vb = blockIdx.x; vb < 440; vb += GRID_) {
    __syncthreads();
    if (vb < 432) {
      // GEMM tile: 16n x 96c, BK=48. (tid<192 active, all 256 hit barriers)
      float* xs = smem;          // 48*16
      float* ps = smem + 768;    // 48*96
      int b = vb / 108;
      int rem = vb % 108;
      int n0 = (rem >> 1) * 16;
      int ch = (rem & 1) * 96;
      int cq = tid % 24, nq = tid / 24;
      int c0 = cq * 4;
      const float* Pm = ws + OFF_P12;
      float acc[4][2];
#pragma unroll
      for (int i = 0; i < 4; ++i) { acc[i][0] = 0.f; acc[i][1] = 0.f; }
      int xrow = tid >> 2, xcol4 = tid & 3;
      for (int kc = 0; kc < 7; ++kc) {
        int t0 = kc * 48;
        if (tid < 192) {
          const float* xr = x + (size_t)(b * T_ + t0 + xrow) * N_;
          if (n0 + 15 < N_) {
            *(float4*)(xs + xrow * 16 + xcol4 * 4) = *(const float4*)(xr + n0 + xcol4 * 4);
          } else {
            float* dst = xs + xrow * 16 + xcol4 * 4;
#pragma unroll
            for (int q = 0; q < 4; ++q) {
              int nn = n0 + xcol4 * 4 + q; if (nn > N_ - 1) nn = N_ - 1;
              dst[q] = xr[nn];
            }
          }
#pragma unroll
          for (int sIdx = 0; sIdx < 6; ++sIdx) {
            int i4 = tid + sIdx * 192;
            int row = i4 / 24, col4 = i4 % 24;
            *(float4*)(ps + row * 96 + col4 * 4) =
                *(const float4*)(Pm + (size_t)(t0 + row) * 192 + ch + col4 * 4);
          }
        }
        __syncthreads();
        if (tid < 192) {
#pragma unroll 6
          for (int kk = 0; kk < 48; ++kk) {
            float x0 = xs[kk * 16 + nq * 2];
            float x1 = xs[kk * 16 + nq * 2 + 1];
            float4 pv = *(const float4*)(ps + kk * 96 + c0);
            acc[0][0] = fmaf(pv.x, x0, acc[0][0]); acc[0][1] = fmaf(pv.x, x1, acc[0][1]);
            acc[1][0] = fmaf(pv.y, x0, acc[1][0]); acc[1][1] = fmaf(pv.y, x1, acc[1][1]);
            acc[2][0] = fmaf(pv.z, x0, acc[2][0]); acc[2][1] = fmaf(pv.z, x1, acc[2][1]);
            acc[3][0] = fmaf(pv.w, x0, acc[3][0]); acc[3][1] = fmaf(pv.w, x1, acc[3][1]);
          }
        }
        __syncthreads();
      }
      if (tid < 192) {
        int n = n0 + nq * 2;
#pragma unroll
        for (int cc = 0; cc < 4; ++cc) {
          float* op = ws + OFF_XPT + ((size_t)(b * 192 + ch + c0 + cc)) * NR + n;
          if (n + 1 < N_) { float2 v; v.x = acc[cc][0]; v.y = acc[cc][1]; *(float2*)op = v; }
          else if (n < N_) { op[0] = acc[cc][0]; }
        }
      }
    } else if (vb < 436) {
      // ---- top-6 / bottom-6 of xbar for batch b, then softmax weights
      float* sx    = smem;         // 864
      float* wkmax = smem + 864;   // 864
      float* wkmin = smem + 1728;  // 864
      float* s_sc  = smem + 2592;  // [4][8]
      float* s_scal = smem + 2624; // 5
      float* selv  = smem + 2629;  // 12
      int*   seli  = (int*)(smem + 2641); // 12
      int b = vb - 432;
      if (tid < 16) {
        int r = tid & 7, which = tid >> 3;
        const float* W = which ? W2 : W1;
        float a = 0.f, bb = 0.f;
        for (int dd = 0; dd < D_; ++dd) {
          float w = W[dd * R_ + r];
          a += We[dd] * w; bb += be[dd] * w;
        }
        s_sc[(which * 2) * 8 + r] = a; s_sc[(which * 2 + 1) * 8 + r] = bb;
      }
      const float invT = 1.f / (float)T_;
      for (int i = tid; i < NB; i += 256) {
        float v = 0.f;
        if (i < N_) {
          const float* xp = ws + OFF_XBP + (size_t)(b * 6) * NB + i;
#pragma unroll
          for (int q = 0; q < 6; ++q) v += xp[q * NB];
          v *= invT;
        }
        sx[i] = v;
        wkmax[i] = (i < N_) ? v : -3.4e38f;
        wkmin[i] = (i < N_) ? v : 3.4e38f;
      }
      __syncthreads();
      if (tid == 0) {
        float s11 = 0.f, s12 = 0.f, s21 = 0.f, s22 = 0.f;
        for (int r = 0; r < R_; ++r) {
          s11 += s_sc[0 * 8 + r] * s_sc[2 * 8 + r];
          s12 += s_sc[0 * 8 + r] * s_sc[3 * 8 + r];
          s21 += s_sc[1 * 8 + r] * s_sc[2 * 8 + r];
          s22 += s_sc[1 * 8 + r] * s_sc[3 * 8 + r];
        }
        s_scal[0] = s11; s_scal[1] = s12; s_scal[2] = s21; s_scal[3] = s22;
        s_scal[4] = 1.f / (1.f + expf(-gate[0]));
      }
      if (tid < 64) {
        int lane = tid;
        for (int r = 0; r < K_; ++r) {
          float bv = -3.4e38f; int bi = 0;
          for (int i = lane; i < N_; i += 64) {
            float v = wkmax[i];
            if (v > bv) { bv = v; bi = i; }
          }
          for (int off = 32; off; off >>= 1) {
            float ov = __shfl_down(bv, off);
            int oi = __shfl_down(bi, off);
            if (ov > bv) { bv = ov; bi = oi; }
          }
          bv = __shfl(bv, 0); bi = __shfl(bi, 0);
          if (lane == 0) { selv[r] = bv; seli[r] = bi; wkmax[bi] = -3.4e38f; }
        }
      } else if (tid < 128) {
        int lane = tid - 64;
        for (int r = 0; r < K_; ++r) {
          float bv = 3.4e38f; int bi = 0;
          for (int i = lane; i < N_; i += 64) {
            float v = wkmin[i];
            if (v < bv) { bv = v; bi = i; }
          }
          for (int off = 32; off; off >>= 1) {
            float ov = __shfl_down(bv, off);
            int oi = __shfl_down(bi, off);
            if (ov < bv) { bv = ov; bi = oi; }
          }
          bv = __shfl(bv, 0); bi = __shfl(bi, 0);
          if (lane == 0) { selv[6 + r] = bv; seli[6 + r] = bi; wkmin[bi] = 3.4e38f; }
        }
      }
      __syncthreads();
      float s11 = s_scal[0], s12 = s_scal[1], s21 = s_scal[2], s22 = s_scal[3];
      float g = s_scal[4];
      const float rsq = 0.3535533906f;
      for (int n = tid; n < N_; n += 256) {
        float xn = sx[n];
        float alpha = (xn * s11 + s21) * rsq;
        float beta  = (xn * s12 + s22) * rsq;
        int base = (alpha >= 0.f) ? 0 : 6;
        float l[K_]; float mx = -3.4e38f;
#pragma unroll
        for (int j = 0; j < K_; ++j) { l[j] = alpha * selv[base + j] + beta; mx = fmaxf(mx, l[j]); }
        float e[K_]; float ss = 0.f;
#pragma unroll
        for (int j = 0; j < K_; ++j) { e[j] = expf(l[j] - mx); ss += e[j]; }
        float sc = g / ss;
#pragma unroll
        for (int j = 0; j < K_; ++j) {
          ws[OFF_WGT + j * (4 * NB) + b * NB + n] = e[j] * sc;
          ((int*)(ws + OFF_IDX))[j * (4 * NB) + b * NB + n] = seli[base + j];
        }
      }
    } else {
      // ---- PC/PA partial column reduce: q sums 84 t's
      int q = vb - 436;
      if (tid < 192) {
        float s = 0.f;
#pragma unroll 12
        for (int t = q * 84; t < q * 84 + 84; ++t) s += ws[OFF_PCP + t * 192 + tid];
        ws[OFF_PCQ + q * 192 + tid] = s;
      }
    }
  }

  grid_barrier((int*)(ws + OFF_BAR) + 8);

  // =============== Phase C: fused mix1 + on-the-fly GCN + assembly ===========
  for (int vb = blockIdx.x; vb < 1536; vb += GRID_) {
    int c = vb >> 2;
    int n = (vb & 3) * 256 + tid;
    if (n >= N_) continue;
    int b = c / P_, p = c % P_;
    const float* Xp1 = ws + OFF_XPT + ((size_t)(b * 192 + p)) * NR;
    const float* Xp2 = ws + OFF_XPT + ((size_t)(b * 192 + P_ + p)) * NR;
    const float* WGTb = ws + OFF_WGT + b * NB;
    const int* IDXb = (const int*)(ws + OFF_IDX) + b * NB;
    float gg = ggcn[0];
    float PCp = 0.f, PAp = 0.f;
#pragma unroll
    for (int q = 0; q < 4; ++q) {
      PCp += ws[OFF_PCQ + q * 192 + p];
      PAp += ws[OFF_PCQ + q * 192 + 96 + p];
    }
    float wj[K_]; int ij[K_];
#pragma unroll
    for (int j = 0; j < K_; ++j) {
      wj[j] = WGTb[j * (4 * NB) + n];
      ij[j] = IDXb[j * (4 * NB) + n];
    }
    float acc1 = Xp1[n];
#pragma unroll
    for (int j = 0; j < K_; ++j) acc1 += wj[j] * Xp1[ij[j]];
    int cnt = ((const int*)(ws + OFF_CNT))[n];
    float S = 0.f;
    if (cnt >= 0) {
      const float* vv = ws + OFF_CSRV;
      const int* ii = (const int*)(ws + OFF_CSRI);
      for (int jj = 0; jj < cnt; ++jj) {
        float a = vv[jj * NB + n];
        int m = ii[jj * NB + n];
        float mix2 = Xp2[m];
        if (m == n) {
#pragma unroll
          for (int j = 0; j < K_; ++j) mix2 += wj[j] * Xp2[ij[j]];
        } else {
#pragma unroll
          for (int j = 0; j < K_; ++j)
            mix2 += WGTb[j * (4 * NB) + m] * Xp2[IDXb[j * (4 * NB) + m]];
        }
        S += a * ws[OFF_DINV + m] * (mix2 + PAp);
      }
    } else {
      const float* ar = A + (size_t)n * N_;
      for (int m = 0; m < N_; ++m) {
        float a = ar[m];
        if (a != 0.f) {
          float mix2 = Xp2[m];
#pragma unroll
          for (int j = 0; j < K_; ++j)
            mix2 += WGTb[j * (4 * NB) + m] * Xp2[IDXb[j * (4 * NB) + m]];
          S += a * ws[OFF_DINV + m] * (mix2 + PAp);
        }
      }
    }
    out[(size_t)c * N_ + n] = acc1 + gg * ws[OFF_DINV + n] * S + PCp + bhead[p];
  }
}

extern "C" void kernel_launch(void* const* d_in, const int* in_sizes, int n_in,
                              void* d_out, int out_size, void* d_ws, size_t ws_size,
                              hipStream_t stream) {
  const float* x     = (const float*)d_in[0];
  const float* We    = (const float*)d_in[1];
  const float* be    = (const float*)d_in[2];
  const float* W1    = (const float*)d_in[3];
  const float* W2    = (const float*)d_in[4];
  const float* gate  = (const float*)d_in[5];
  const float* A     = (const float*)d_in[6];
  const float* Wgcn  = (const float*)d_in[7];
  const float* ggcn  = (const float*)d_in[8];
  const float* Whead = (const float*)d_in[9];
  const float* bhead = (const float*)d_in[10];
  float* ws = (float*)d_ws;
  float* out = (float*)d_out;

  // zero the two grid-barrier counters (capture-legal async memset)
  hipMemsetAsync(ws + OFF_BAR, 0, 64 * sizeof(float), stream);

  kFused<<<GRID_, 256, 0, stream>>>(x, We, be, W1, W2, gate, A, Wgcn, ggcn,
                                    Whead, bhead, ws, out);
}

// Round 3
// 108.832 us; speedup vs baseline: 3.8811x; 3.8811x over previous
//
#include <hip/hip_runtime.h>
#include <math.h>

#define B_ 4
#define T_ 336
#define N_ 862
#define D_ 64
#define R_ 8
#define K_ 6
#define P_ 96
#define NR 896   // padded n-stride
#define CAP 32   // CSR cap per row
#define NB 864   // padded 862

// workspace float offsets (re-laid-out for interleaved WGT/IDX cells)
#define OFF_PCQ  0        // 4*192 partial PC/PA
#define OFF_XBP  768      // 4*6*864 xbar t-partials
#define OFF_DINV 21504    // 864
#define OFF_WGI  22368    // 4*864*16: per-(b,n) 64B cell: w0..3 | w4,w5,i0,i1 | i2..5 | pad
#define OFF_CNT  77664    // 864 int
#define OFF_CSRV 78528    // 32*864 (j-major)
#define OFF_CSRI 106176   // 32*864 int
#define OFF_P12  133824   // 336*192
#define OFF_PCP  198336   // 336*192 per-t partials of PC/PA
#define OFF_XPT  262848   // 4*192*896 = 688128 (end 950976)

// ---------------- Phase A: proj (336) + xbar partials (336) + CSR/dinv (288).
// grid 960 x 192.
__global__ __launch_bounds__(192) void kA_prep(const float* __restrict__ x,
                                               const float* __restrict__ Whead,
                                               const float* __restrict__ A,
                                               const float* __restrict__ We,
                                               const float* __restrict__ be,
                                               const float* __restrict__ gate,
                                               const float* __restrict__ Wgcn,
                                               float* __restrict__ ws) {
  int id = blockIdx.x;
  int tid = threadIdx.x;
  if (id < 336) {
    // ---- projection for t = id: P12[t][c], PCP[t][c]
    __shared__ float sW1[64], sW2[64], sCB[64], sWe[64];
    int t = id;
    float g = 1.f / (1.f + expf(-gate[0]));
    if (tid < 64) {
      float a = 0.f;
#pragma unroll
      for (int dd = 0; dd < D_; ++dd) a += We[dd] * Wgcn[dd * D_ + tid];
      sW1[tid] = a;
    } else if (tid < 128) {
      int e = tid - 64;
      float a = 0.f;
#pragma unroll
      for (int dd = 0; dd < D_; ++dd) a += be[dd] * Wgcn[dd * D_ + e];
      sW2[e] = (1.f + g) * a;
    } else {
      int e = tid - 128;
      sCB[e] = (1.f + g) * be[e];
      sWe[e] = We[e];
    }
    __syncthreads();
    int c = tid, p = c % P_, sel = c / P_;
    const float* cA = sel ? sW1 : sWe;
    const float* cB = sel ? sW2 : sCB;
    const float* wrow = Whead + (size_t)t * D_ * P_ + p;
    float a = 0.f, bacc = 0.f;
#pragma unroll
    for (int e = 0; e < D_; ++e) {
      float w = wrow[(size_t)e * P_];
      a = fmaf(cA[e], w, a);
      bacc = fmaf(cB[e], w, bacc);
    }
    ws[OFF_P12 + t * 192 + c] = a;
    ws[OFF_PCP + t * 192 + c] = bacc;
  } else if (id < 672) {
    // ---- xbar t-partials: block = (b, 64-n chunk, t-group of 56)
    __shared__ float part[192];
    int iq = id - 336;
    int b = iq / 84, rem = iq % 84;
    int ch = rem / 6, tg = rem % 6;
    int lane = tid & 63, tsub = tid >> 6;
    int n = ch * 64 + lane;
    float s = 0.f;
    if (n < N_) {
      const float* xp = x + (size_t)(b * T_) * N_ + n;
      int tend = tg * 56 + 56;
#pragma unroll 4
      for (int t = tg * 56 + tsub; t < tend; t += 3) s += xp[(size_t)t * N_];
    }
    part[tid] = s;
    __syncthreads();
    if (tsub == 0 && n < N_)
      ws[OFF_XBP + (size_t)(b * 6 + tg) * NB + n] =
          part[lane] + part[64 + lane] + part[128 + lane];
  } else {
    // ---- CSR + dinv: 3 rows per block, one per wave
    int lane = tid & 63, wv = tid >> 6;
    int n = (id - 672) * 3 + wv;
    if (n >= N_) return;
    const float* ap = A + (size_t)n * N_;
    float* vout = ws + OFF_CSRV;
    int* iout = (int*)(ws + OFF_CSRI);
    float s = 0.f;
    int total = 0;
    for (int base = 0; base < N_; base += 64) {
      int m = base + lane;
      float a = (m < N_) ? ap[m] : 0.f;
      s += a;
      bool nz = (a != 0.f);
      unsigned long long mask = __ballot(nz);
      int pos = __popcll(mask & ((1ull << lane) - 1ull));
      if (nz) {
        int slot = total + pos;
        if (slot < CAP) { vout[slot * NB + n] = a; iout[slot * NB + n] = m; }
      }
      total += __popcll(mask);
    }
    for (int off = 32; off; off >>= 1) s += __shfl_down(s, off);
    if (lane == 0) {
      ws[OFF_DINV + n] = (s > 0.f) ? (1.f / sqrtf(s)) : 0.f;
      ((int*)(ws + OFF_CNT))[n] = (total <= CAP) ? total : -1;
    }
  }
}

// ---------------- Phase B: GEMM (432: 16n x 96c, double-buffered) + topk (4)
// + PC/PA partials (4).  grid 440 x 192.
__global__ __launch_bounds__(192) void kM_mid(const float* __restrict__ x,
                                              const float* __restrict__ W1,
                                              const float* __restrict__ W2,
                                              const float* __restrict__ We,
                                              const float* __restrict__ be,
                                              const float* __restrict__ gate,
                                              float* __restrict__ ws) {
  __shared__ float smem[10752];   // GEMM dbuf: 2*768 xs + 2*4608 ps = 43 KB
  int id = blockIdx.x;
  int tid = threadIdx.x;
  if (id < 432) {
    // GEMM tile: 16n x 96c, BK=48, double-buffered LDS (1 barrier/K-step).
    float* xs = smem;            // 2 x 48*16
    float* ps = smem + 1536;     // 2 x 48*96
    int b = id / 108;
    int rem = id % 108;
    int n0 = (rem >> 1) * 16;
    int ch = (rem & 1) * 96;   // c-half offset
    int cq = tid % 24, nq = tid / 24;   // nq in [0,8)
    int c0 = cq * 4;
    const float* P = ws + OFF_P12;
    float acc[4][2];
#pragma unroll
    for (int i = 0; i < 4; ++i) { acc[i][0] = 0.f; acc[i][1] = 0.f; }
    int xrow = tid >> 2, xcol4 = tid & 3;

    auto stage = [&](int kc, int buf) {
      int t0 = kc * 48;
      float* xd = xs + buf * 768;
      float* pd = ps + buf * 4608;
      const float* xr = x + (size_t)(b * T_ + t0 + xrow) * N_;
      if (n0 + 15 < N_) {
        *(float4*)(xd + xrow * 16 + xcol4 * 4) = *(const float4*)(xr + n0 + xcol4 * 4);
      } else {
        float* dst = xd + xrow * 16 + xcol4 * 4;
#pragma unroll
        for (int q = 0; q < 4; ++q) {
          int nn = n0 + xcol4 * 4 + q; if (nn > N_ - 1) nn = N_ - 1;
          dst[q] = xr[nn];
        }
      }
#pragma unroll
      for (int sIdx = 0; sIdx < 6; ++sIdx) {
        int i4 = tid + sIdx * 192;
        int row = i4 / 24, col4 = i4 % 24;
        *(float4*)(pd + row * 96 + col4 * 4) =
            *(const float4*)(P + (size_t)(t0 + row) * 192 + ch + col4 * 4);
      }
    };

    stage(0, 0);
    __syncthreads();
    for (int kc = 0; kc < 7; ++kc) {
      int cur = kc & 1;
      if (kc < 6) stage(kc + 1, cur ^ 1);   // overlap next-tile loads w/ compute
      const float* xsC = xs + cur * 768;
      const float* psC = ps + cur * 4608;
#pragma unroll 6
      for (int kk = 0; kk < 48; ++kk) {
        float x0 = xsC[kk * 16 + nq * 2];
        float x1 = xsC[kk * 16 + nq * 2 + 1];
        float4 pv = *(const float4*)(psC + kk * 96 + c0);
        acc[0][0] = fmaf(pv.x, x0, acc[0][0]); acc[0][1] = fmaf(pv.x, x1, acc[0][1]);
        acc[1][0] = fmaf(pv.y, x0, acc[1][0]); acc[1][1] = fmaf(pv.y, x1, acc[1][1]);
        acc[2][0] = fmaf(pv.z, x0, acc[2][0]); acc[2][1] = fmaf(pv.z, x1, acc[2][1]);
        acc[3][0] = fmaf(pv.w, x0, acc[3][0]); acc[3][1] = fmaf(pv.w, x1, acc[3][1]);
      }
      __syncthreads();   // staged stores done + compute-read of cur done
    }
    int n = n0 + nq * 2;
#pragma unroll
    for (int cc = 0; cc < 4; ++cc) {
      float* op = ws + OFF_XPT + ((size_t)(b * 192 + ch + c0 + cc)) * NR + n;
      if (n + 1 < N_) { float2 v; v.x = acc[cc][0]; v.y = acc[cc][1]; *(float2*)op = v; }
      else if (n < N_) { op[0] = acc[cc][0]; }
    }
  } else if (id < 436) {
    // ---- top-6 / bottom-6 of xbar for batch b, then softmax weights
    __shared__ float s_sc[4][R_];
    __shared__ float s_scal[5];
    __shared__ float selv[12];
    __shared__ int seli[12];
    float* sx = smem;            // 864
    float* wkmax = smem + 864;   // 864
    float* wkmin = smem + 1728;  // 864
    int b = id - 432;
    if (tid < 16) {
      int r = tid & 7, which = tid >> 3;
      const float* W = which ? W2 : W1;
      float a = 0.f, bb = 0.f;
      for (int dd = 0; dd < D_; ++dd) {
        float w = W[dd * R_ + r];
        a += We[dd] * w; bb += be[dd] * w;
      }
      s_sc[which * 2][r] = a; s_sc[which * 2 + 1][r] = bb;
    }
    const float invT = 1.f / (float)T_;
    for (int i = tid; i < NB; i += 192) {
      float v = 0.f;
      if (i < N_) {
        const float* xp = ws + OFF_XBP + (size_t)(b * 6) * NB + i;
#pragma unroll
        for (int q = 0; q < 6; ++q) v += xp[q * NB];
        v *= invT;
      }
      sx[i] = v;
      wkmax[i] = (i < N_) ? v : -3.4e38f;
      wkmin[i] = (i < N_) ? v : 3.4e38f;
    }
    __syncthreads();
    if (tid == 0) {
      float s11 = 0.f, s12 = 0.f, s21 = 0.f, s22 = 0.f;
      for (int r = 0; r < R_; ++r) {
        s11 += s_sc[0][r] * s_sc[2][r];
        s12 += s_sc[0][r] * s_sc[3][r];
        s21 += s_sc[1][r] * s_sc[2][r];
        s22 += s_sc[1][r] * s_sc[3][r];
      }
      s_scal[0] = s11; s_scal[1] = s12; s_scal[2] = s21; s_scal[3] = s22;
      s_scal[4] = 1.f / (1.f + expf(-gate[0]));
    }
    if (tid < 64) {
      int lane = tid;
      for (int r = 0; r < K_; ++r) {
        float bv = -3.4e38f; int bi = 0;
        for (int i = lane; i < N_; i += 64) {
          float v = wkmax[i];
          if (v > bv) { bv = v; bi = i; }
        }
        for (int off = 32; off; off >>= 1) {
          float ov = __shfl_down(bv, off);
          int oi = __shfl_down(bi, off);
          if (ov > bv) { bv = ov; bi = oi; }
        }
        bv = __shfl(bv, 0); bi = __shfl(bi, 0);
        if (lane == 0) { selv[r] = bv; seli[r] = bi; wkmax[bi] = -3.4e38f; }
      }
    } else if (tid < 128) {
      int lane = tid - 64;
      for (int r = 0; r < K_; ++r) {
        float bv = 3.4e38f; int bi = 0;
        for (int i = lane; i < N_; i += 64) {
          float v = wkmin[i];
          if (v < bv) { bv = v; bi = i; }
        }
        for (int off = 32; off; off >>= 1) {
          float ov = __shfl_down(bv, off);
          int oi = __shfl_down(bi, off);
          if (ov < bv) { bv = ov; bi = oi; }
        }
        bv = __shfl(bv, 0); bi = __shfl(bi, 0);
        if (lane == 0) { selv[6 + r] = bv; seli[6 + r] = bi; wkmin[bi] = 3.4e38f; }
      }
    }
    __syncthreads();
    float s11 = s_scal[0], s12 = s_scal[1], s21 = s_scal[2], s22 = s_scal[3];
    float g = s_scal[4];
    const float rsq = 0.3535533906f;
    for (int n = tid; n < N_; n += 192) {
      float xn = sx[n];
      float alpha = (xn * s11 + s21) * rsq;
      float beta  = (xn * s12 + s22) * rsq;
      int base = (alpha >= 0.f) ? 0 : 6;
      float l[K_]; float mx = -3.4e38f;
#pragma unroll
      for (int j = 0; j < K_; ++j) { l[j] = alpha * selv[base + j] + beta; mx = fmaxf(mx, l[j]); }
      float e[K_]; float ss = 0.f;
#pragma unroll
      for (int j = 0; j < K_; ++j) { e[j] = expf(l[j] - mx); ss += e[j]; }
      float sc = g / ss;
      // interleaved 64B cell: 3x float4
      float4 v0, v1, v2;
      v0.x = e[0] * sc; v0.y = e[1] * sc; v0.z = e[2] * sc; v0.w = e[3] * sc;
      v1.x = e[4] * sc; v1.y = e[5] * sc;
      v1.z = __int_as_float(seli[base + 0]); v1.w = __int_as_float(seli[base + 1]);
      v2.x = __int_as_float(seli[base + 2]); v2.y = __int_as_float(seli[base + 3]);
      v2.z = __int_as_float(seli[base + 4]); v2.w = __int_as_float(seli[base + 5]);
      float* cell = ws + OFF_WGI + ((size_t)(b * NB + n)) * 16;
      *(float4*)cell = v0;
      *(float4*)(cell + 4) = v1;
      *(float4*)(cell + 8) = v2;
    }
  } else {
    // ---- PC/PA partial column reduce: block q sums 84 t's
    int q = id - 436;
    if (tid < 192) {
      float s = 0.f;
#pragma unroll 12
      for (int t = q * 84; t < q * 84 + 84; ++t) s += ws[OFF_PCP + t * 192 + tid];
      ws[OFF_PCQ + q * 192 + tid] = s;
    }
  }
}

// ---------------- Phase C: fused mix1 + on-the-fly GCN + assembly.
// grid(4,384) x 256. blockIdx.y = c = b*96+p.
__global__ __launch_bounds__(256) void kF_final(const float* __restrict__ A,
                                                const float* __restrict__ bhead,
                                                const float* __restrict__ ggcn,
                                                const float* __restrict__ ws,
                                                float* __restrict__ out) {
  int c = blockIdx.y;
  int n = blockIdx.x * 256 + threadIdx.x;
  if (n >= N_) return;
  int b = c / P_, p = c % P_;
  const float* Xp1 = ws + OFF_XPT + ((size_t)(b * 192 + p)) * NR;
  const float* Xp2 = ws + OFF_XPT + ((size_t)(b * 192 + P_ + p)) * NR;
  const float* WGIb = ws + OFF_WGI + (size_t)b * NB * 16;
  float gg = ggcn[0];
  float PCp = 0.f, PAp = 0.f;
#pragma unroll
  for (int q = 0; q < 4; ++q) {
    PCp += ws[OFF_PCQ + q * 192 + p];
    PAp += ws[OFF_PCQ + q * 192 + 96 + p];
  }
  // own cell: 3x float4
  const float* cell = WGIb + (size_t)n * 16;
  float4 u0 = *(const float4*)cell;
  float4 u1 = *(const float4*)(cell + 4);
  float4 u2 = *(const float4*)(cell + 8);
  float wj[K_]; int ij[K_];
  wj[0] = u0.x; wj[1] = u0.y; wj[2] = u0.z; wj[3] = u0.w;
  wj[4] = u1.x; wj[5] = u1.y;
  ij[0] = __float_as_int(u1.z); ij[1] = __float_as_int(u1.w);
  ij[2] = __float_as_int(u2.x); ij[3] = __float_as_int(u2.y);
  ij[4] = __float_as_int(u2.z); ij[5] = __float_as_int(u2.w);
  float acc1 = Xp1[n];
#pragma unroll
  for (int j = 0; j < K_; ++j) acc1 += wj[j] * Xp1[ij[j]];
  int cnt = ((const int*)(ws + OFF_CNT))[n];
  float S = 0.f;
  if (cnt >= 0) {
    const float* vv = ws + OFF_CSRV;
    const int* ii = (const int*)(ws + OFF_CSRI);
    for (int jj = 0; jj < cnt; ++jj) {
      float a = vv[jj * NB + n];
      int m = ii[jj * NB + n];
      float mix2 = Xp2[m];
      if (m == n) {
#pragma unroll
        for (int j = 0; j < K_; ++j) mix2 += wj[j] * Xp2[ij[j]];
      } else {
        const float* mc = WGIb + (size_t)m * 16;
        float4 a0 = *(const float4*)mc;
        float4 a1 = *(const float4*)(mc + 4);
        float4 a2 = *(const float4*)(mc + 8);
        mix2 += a0.x * Xp2[__float_as_int(a1.z)] + a0.y * Xp2[__float_as_int(a1.w)]
              + a0.z * Xp2[__float_as_int(a2.x)] + a0.w * Xp2[__float_as_int(a2.y)]
              + a1.x * Xp2[__float_as_int(a2.z)] + a1.y * Xp2[__float_as_int(a2.w)];
      }
      S += a * ws[OFF_DINV + m] * (mix2 + PAp);
    }
  } else {
    const float* ar = A + (size_t)n * N_;
    for (int m = 0; m < N_; ++m) {
      float a = ar[m];
      if (a != 0.f) {
        const float* mc = WGIb + (size_t)m * 16;
        float4 a0 = *(const float4*)mc;
        float4 a1 = *(const float4*)(mc + 4);
        float4 a2 = *(const float4*)(mc + 8);
        float mix2 = Xp2[m]
              + a0.x * Xp2[__float_as_int(a1.z)] + a0.y * Xp2[__float_as_int(a1.w)]
              + a0.z * Xp2[__float_as_int(a2.x)] + a0.w * Xp2[__float_as_int(a2.y)]
              + a1.x * Xp2[__float_as_int(a2.z)] + a1.y * Xp2[__float_as_int(a2.w)];
        S += a * ws[OFF_DINV + m] * (mix2 + PAp);
      }
    }
  }
  out[(size_t)c * N_ + n] = acc1 + gg * ws[OFF_DINV + n] * S + PCp + bhead[p];
}

extern "C" void kernel_launch(void* const* d_in, const int* in_sizes, int n_in,
                              void* d_out, int out_size, void* d_ws, size_t ws_size,
                              hipStream_t stream) {
  const float* x     = (const float*)d_in[0];
  const float* We    = (const float*)d_in[1];
  const float* be    = (const float*)d_in[2];
  const float* W1    = (const float*)d_in[3];
  const float* W2    = (const float*)d_in[4];
  const float* gate  = (const float*)d_in[5];
  const float* A     = (const float*)d_in[6];
  const float* Wgcn  = (const float*)d_in[7];
  const float* ggcn  = (const float*)d_in[8];
  const float* Whead = (const float*)d_in[9];
  const float* bhead = (const float*)d_in[10];
  float* ws = (float*)d_ws;
  float* out = (float*)d_out;

  kA_prep<<<960, 192, 0, stream>>>(x, Whead, A, We, be, gate, Wgcn, ws);
  kM_mid<<<440, 192, 0, stream>>>(x, W1, W2, We, be, gate, ws);
  kF_final<<<dim3(4, 384), 256, 0, stream>>>(A, bhead, ggcn, ws, out);
}